// Round 1
// baseline (435.828 us; speedup 1.0000x reference)
//
#include <hip/hip_runtime.h>
#include <hip/hip_bf16.h>

#define B_ 8
#define S_ 2048
#define DM 1024
#define DH 64
#define M_ (B_ * S_)   // 16384

// ---------------------------------------------------------------------------
// Projection: Y[M][64] = X[M][1024] @ W[64][1024]^T   (torch Linear, no bias)
// grid = (M/64, 3), block = 256.  blockIdx.y selects q/k/v.
// LDS tiles stored K-major (transposed) so the inner loop does float4 reads.
// ---------------------------------------------------------------------------
__global__ __launch_bounds__(256) void proj_kernel(
    const float* __restrict__ X0, const float* __restrict__ X1,
    const float* __restrict__ X2, const float* __restrict__ W0,
    const float* __restrict__ W1, const float* __restrict__ W2,
    float* __restrict__ Yb) {
    __shared__ float Xt[64][68];  // [k][row]
    __shared__ float Wt[64][68];  // [k][head]

    const int g = blockIdx.y;
    const float* X = (g == 0) ? X0 : (g == 1) ? X1 : X2;
    const float* W = (g == 0) ? W0 : (g == 1) ? W1 : W2;
    float* Y = Yb + (size_t)g * ((size_t)M_ * DH);

    const int t = threadIdx.x;
    const int row0 = blockIdx.x * 64;
    const int tr = t >> 4;   // 0..15 -> rows tr*4..tr*4+3
    const int tc = t & 15;   // 0..15 -> heads tc*4..tc*4+3

    float acc[4][4];
#pragma unroll
    for (int i = 0; i < 4; ++i)
#pragma unroll
        for (int j = 0; j < 4; ++j) acc[i][j] = 0.f;

    for (int kt = 0; kt < DM; kt += 64) {
#pragma unroll
        for (int i = 0; i < 16; ++i) {
            int idx = t + i * 256;
            int rr = idx >> 6, cc = idx & 63;
            Xt[cc][rr] = X[(size_t)(row0 + rr) * DM + kt + cc];
            Wt[cc][rr] = W[(size_t)rr * DM + kt + cc];
        }
        __syncthreads();
#pragma unroll
        for (int kk = 0; kk < 64; ++kk) {
            float4 av = *(const float4*)&Xt[kk][tr * 4];
            float4 bv = *(const float4*)&Wt[kk][tc * 4];
            const float* a = &av.x;
            const float* b = &bv.x;
#pragma unroll
            for (int i = 0; i < 4; ++i)
#pragma unroll
                for (int j = 0; j < 4; ++j) acc[i][j] += a[i] * b[j];
        }
        __syncthreads();
    }
#pragma unroll
    for (int i = 0; i < 4; ++i) {
        float4 ov = make_float4(acc[i][0], acc[i][1], acc[i][2], acc[i][3]);
        *(float4*)&Y[(size_t)(row0 + tr * 4 + i) * DH + tc * 4] = ov;
    }
}

// ---------------------------------------------------------------------------
// Causal flash attention over projected Q,K,V [B][S][64] -> Out [B][S][64]
// grid = (S/64, B), block = 256. 64-row Q tile per block; K/V tiles of 64.
// Per-thread 4x4 score tile (tr: row group, tc: col group); online softmax
// with shfl_xor reductions across the 16 lanes sharing a row.
// ---------------------------------------------------------------------------
__global__ __launch_bounds__(256) void attn_kernel(
    const float* __restrict__ Qp, const float* __restrict__ Kp,
    const float* __restrict__ Vp, float* __restrict__ Out) {
    __shared__ float Qt[64][68];  // [d][row]
    __shared__ float Kt[64][68];  // [d][col]
    __shared__ float Vs[64][68];  // [row][d]
    __shared__ float Ps[64][68];  // [row][col]

    const int t = threadIdx.x;
    const int b = blockIdx.y;
    const int qt = blockIdx.x;
    const int tr = t >> 4;  // 0..15 -> rows tr*4..+3
    const int tc = t & 15;  // 0..15 -> cols/dims tc*4..+3

    const float* Qb = Qp + (size_t)b * S_ * DH;
    const float* Kb = Kp + (size_t)b * S_ * DH;
    const float* Vb = Vp + (size_t)b * S_ * DH;

#pragma unroll
    for (int i = 0; i < 16; ++i) {
        int idx = t + i * 256;
        int rr = idx >> 6, cc = idx & 63;
        Qt[cc][rr] = Qb[(size_t)(qt * 64 + rr) * DH + cc];
    }
    __syncthreads();

    float m[4], l[4], o[4][4];
#pragma unroll
    for (int i = 0; i < 4; ++i) {
        m[i] = -1e30f;
        l[i] = 0.f;
#pragma unroll
        for (int j = 0; j < 4; ++j) o[i][j] = 0.f;
    }

    const float scale = 0.125f;  // 1/sqrt(64)

    for (int kt = 0; kt <= qt; ++kt) {
#pragma unroll
        for (int i = 0; i < 16; ++i) {
            int idx = t + i * 256;
            int rr = idx >> 6, cc = idx & 63;
            Kt[cc][rr] = Kb[(size_t)(kt * 64 + rr) * DH + cc];
            Vs[rr][cc] = Vb[(size_t)(kt * 64 + rr) * DH + cc];
        }
        __syncthreads();

        // --- scores: 4x4 per thread over d=0..63 ---
        float s[4][4];
#pragma unroll
        for (int i = 0; i < 4; ++i)
#pragma unroll
            for (int j = 0; j < 4; ++j) s[i][j] = 0.f;

#pragma unroll 4
        for (int d = 0; d < 64; ++d) {
            float4 av = *(const float4*)&Qt[d][tr * 4];
            float4 bv = *(const float4*)&Kt[d][tc * 4];
            const float* a = &av.x;
            const float* bb = &bv.x;
#pragma unroll
            for (int i = 0; i < 4; ++i)
#pragma unroll
                for (int j = 0; j < 4; ++j) s[i][j] += a[i] * bb[j];
        }

        // --- scale + causal mask ---
#pragma unroll
        for (int i = 0; i < 4; ++i) {
            int rg = qt * 64 + tr * 4 + i;
#pragma unroll
            for (int j = 0; j < 4; ++j) {
                int cg = kt * 64 + tc * 4 + j;
                s[i][j] = (cg <= rg) ? s[i][j] * scale : -1e30f;
            }
        }

        // --- online softmax update per row ---
#pragma unroll
        for (int i = 0; i < 4; ++i) {
            float mx = fmaxf(fmaxf(s[i][0], s[i][1]), fmaxf(s[i][2], s[i][3]));
#pragma unroll
            for (int off = 1; off < 16; off <<= 1)
                mx = fmaxf(mx, __shfl_xor(mx, off, 64));
            float mn = fmaxf(m[i], mx);
            float corr = __expf(m[i] - mn);
            float ls = 0.f;
#pragma unroll
            for (int j = 0; j < 4; ++j) {
                s[i][j] = __expf(s[i][j] - mn);
                ls += s[i][j];
            }
#pragma unroll
            for (int off = 1; off < 16; off <<= 1) ls += __shfl_xor(ls, off, 64);
            l[i] = l[i] * corr + ls;
            m[i] = mn;
#pragma unroll
            for (int j = 0; j < 4; ++j) o[i][j] *= corr;
        }

        // --- share P through LDS ---
#pragma unroll
        for (int i = 0; i < 4; ++i) {
            float4 pv = make_float4(s[i][0], s[i][1], s[i][2], s[i][3]);
            *(float4*)&Ps[tr * 4 + i][tc * 4] = pv;
        }
        __syncthreads();

        // --- PV: o[i][dd] += sum_j P[row_i][j] * V[j][dim_dd] ---
#pragma unroll 4
        for (int j = 0; j < 64; ++j) {
            float4 vv = *(const float4*)&Vs[j][tc * 4];
            const float* v4 = &vv.x;
            float p0 = Ps[tr * 4 + 0][j];
            float p1 = Ps[tr * 4 + 1][j];
            float p2 = Ps[tr * 4 + 2][j];
            float p3 = Ps[tr * 4 + 3][j];
#pragma unroll
            for (int dd = 0; dd < 4; ++dd) {
                o[0][dd] += p0 * v4[dd];
                o[1][dd] += p1 * v4[dd];
                o[2][dd] += p2 * v4[dd];
                o[3][dd] += p3 * v4[dd];
            }
        }
        __syncthreads();
    }

#pragma unroll
    for (int i = 0; i < 4; ++i) {
        float inv = 1.f / l[i];
        float4 ov = make_float4(o[i][0] * inv, o[i][1] * inv, o[i][2] * inv,
                                o[i][3] * inv);
        *(float4*)&Out[((size_t)b * S_ + qt * 64 + tr * 4 + i) * DH + tc * 4] = ov;
    }
}

extern "C" void kernel_launch(void* const* d_in, const int* in_sizes, int n_in,
                              void* d_out, int out_size, void* d_ws,
                              size_t ws_size, hipStream_t stream) {
    const float* q_in = (const float*)d_in[0];
    const float* k_in = (const float*)d_in[1];
    const float* v_in = (const float*)d_in[2];
    const float* wq = (const float*)d_in[3];
    const float* wk = (const float*)d_in[4];
    const float* wv = (const float*)d_in[5];
    float* out = (float*)d_out;

    float* ws_f = (float*)d_ws;
    const size_t MD = (size_t)M_ * DH;  // 1048576
    float* Qp = ws_f;
    float* Kp = ws_f + MD;
    float* Vp = ws_f + 2 * MD;

    proj_kernel<<<dim3(M_ / 64, 3), 256, 0, stream>>>(q_in, k_in, v_in, wq, wk,
                                                      wv, ws_f);
    attn_kernel<<<dim3(S_ / 64, B_), 256, 0, stream>>>(Qp, Kp, Vp, out);
}

// Round 2
// 317.837 us; speedup vs baseline: 1.3712x; 1.3712x over previous
//
#include <hip/hip_runtime.h>
#include <hip/hip_bf16.h>
#include <stdint.h>

#define B_ 8
#define S_ 2048
#define DM 1024
#define DH 64
#define M_ (B_ * S_)  // 16384

typedef __attribute__((ext_vector_type(8))) short bf16x8;  // 8 bf16 = 4 VGPR
typedef __attribute__((ext_vector_type(4))) float f32x4;   // MFMA C/D frag

// fp32 -> bf16 round-to-nearest-even
__device__ __forceinline__ ushort f2bf(float x) {
    union { float f; uint32_t u; } v;
    v.f = x;
    uint32_t r = v.u + 0x7FFFu + ((v.u >> 16) & 1u);
    return (ushort)(r >> 16);
}

// Swizzled LDS address for a [64 rows][64 bf16] tile (128 B row stride).
// XOR of (row&7)<<4 spreads the 16B column slots across 8 bank groups:
// fragment reads (16 lanes, same 16B col, rows 0..15) become 2-way = free.
__device__ __forceinline__ void* swz(void* base, int row, int kbyte) {
    int byte = row * 128 + kbyte;
    byte ^= (row & 7) << 4;
    return (void*)((char*)base + byte);
}

// ---------------------------------------------------------------------------
// Projection: Y = X[16384,1024] @ W[64,1024]^T, bf16 MFMA, fp32 in / bf16 out.
// grid=(256,3) block=256. BM=64, BN=64, BK=64; 4 waves 2x2, wave tile 32x32.
// g==2 (V) writes transposed output Vt[b][dh][s].
// MFMA 16x16x32 fragment maps used everywhere:
//   A[i][k]: lane = i + 16*(k/8), elem = k%8
//   B[k][j]: lane = j + 16*(k/8), elem = k%8
//   D[i][j]: lane = j + 16*(i/4) ; reg = i%4   (HW-verified)
// ---------------------------------------------------------------------------
__global__ __launch_bounds__(256) void proj_kernel(
    const float* __restrict__ X0, const float* __restrict__ X1,
    const float* __restrict__ X2, const float* __restrict__ W0,
    const float* __restrict__ W1, const float* __restrict__ W2,
    ushort* __restrict__ Qp, ushort* __restrict__ Kp,
    ushort* __restrict__ Vt) {
    __shared__ __align__(16) ushort Xs[64 * 64];
    __shared__ __align__(16) ushort Ws[64 * 64];

    const int g = blockIdx.y;
    const float* X = (g == 0) ? X0 : (g == 1) ? X1 : X2;
    const float* W = (g == 0) ? W0 : (g == 1) ? W1 : W2;

    const int t = threadIdx.x;
    const int row0 = blockIdx.x * 64;
    const int wid = t >> 6, lane = t & 63;
    const int wr = wid >> 1, wc = wid & 1;
    const int lr = lane & 15, lg = lane >> 4;

    f32x4 acc[2][2] = {};

    for (int kt = 0; kt < DM; kt += 64) {
        // stage 64x64 fp32 -> bf16 LDS (X rows = seq rows, W rows = heads)
#pragma unroll
        for (int i = 0; i < 4; ++i) {
            int idx = t + i * 256;
            int row = idx >> 4, kq = idx & 15;
            float4 xv = *(const float4*)&X[(size_t)(row0 + row) * DM + kt + kq * 4];
            uint32_t xlo = f2bf(xv.x) | ((uint32_t)f2bf(xv.y) << 16);
            uint32_t xhi = f2bf(xv.z) | ((uint32_t)f2bf(xv.w) << 16);
            *(uint2*)swz(Xs, row, kq * 8) = make_uint2(xlo, xhi);
            float4 wv = *(const float4*)&W[(size_t)row * DM + kt + kq * 4];
            uint32_t wlo = f2bf(wv.x) | ((uint32_t)f2bf(wv.y) << 16);
            uint32_t whi = f2bf(wv.z) | ((uint32_t)f2bf(wv.w) << 16);
            *(uint2*)swz(Ws, row, kq * 8) = make_uint2(wlo, whi);
        }
        __syncthreads();
#pragma unroll
        for (int ks = 0; ks < 2; ++ks) {
            bf16x8 a0 = *(bf16x8*)swz(Xs, wr * 32 + lr,      ks * 64 + lg * 16);
            bf16x8 a1 = *(bf16x8*)swz(Xs, wr * 32 + 16 + lr, ks * 64 + lg * 16);
            bf16x8 b0 = *(bf16x8*)swz(Ws, wc * 32 + lr,      ks * 64 + lg * 16);
            bf16x8 b1 = *(bf16x8*)swz(Ws, wc * 32 + 16 + lr, ks * 64 + lg * 16);
            acc[0][0] = __builtin_amdgcn_mfma_f32_16x16x32_bf16(a0, b0, acc[0][0], 0, 0, 0);
            acc[0][1] = __builtin_amdgcn_mfma_f32_16x16x32_bf16(a0, b1, acc[0][1], 0, 0, 0);
            acc[1][0] = __builtin_amdgcn_mfma_f32_16x16x32_bf16(a1, b0, acc[1][0], 0, 0, 0);
            acc[1][1] = __builtin_amdgcn_mfma_f32_16x16x32_bf16(a1, b1, acc[1][1], 0, 0, 0);
        }
        __syncthreads();
    }

    if (g < 2) {
        ushort* Y = (g == 0) ? Qp : Kp;
#pragma unroll
        for (int fi = 0; fi < 2; ++fi)
#pragma unroll
            for (int fj = 0; fj < 2; ++fj)
#pragma unroll
                for (int r = 0; r < 4; ++r) {
                    int row = row0 + wr * 32 + fi * 16 + lg * 4 + r;
                    int col = wc * 32 + fj * 16 + lr;
                    Y[(size_t)row * DH + col] = f2bf(acc[fi][fj][r]);
                }
    } else {
        // V transposed: Vt[b][dh][s]; lane's 4 regs are 4 consecutive s.
        const int bb = row0 >> 11;
        const int s0 = row0 & 2047;
#pragma unroll
        for (int fi = 0; fi < 2; ++fi)
#pragma unroll
            for (int fj = 0; fj < 2; ++fj) {
                int dh = wc * 32 + fj * 16 + lr;
                int s = s0 + wr * 32 + fi * 16 + lg * 4;
                ushort4 pk;
                pk.x = f2bf(acc[fi][fj][0]);
                pk.y = f2bf(acc[fi][fj][1]);
                pk.z = f2bf(acc[fi][fj][2]);
                pk.w = f2bf(acc[fi][fj][3]);
                *(ushort4*)&Vt[((size_t)bb * DH + dh) * S_ + s] = pk;
            }
    }
}

// ---------------------------------------------------------------------------
// Causal flash attention, per-wave. QBLK=16 rows/wave, KVBLK=64.
// grid=(32,8) block=256 (4 waves; wave w owns Q-tile blockIdx.x*4+w).
// Q/K row-major bf16, V transposed bf16 (Vt[b][dh][s]). All MFMA operands are
// direct 16B global loads except P, which round-trips a per-wave LDS buffer
// to convert the D-layout (col-per-lane) into the A-layout (row-per-lane).
// ---------------------------------------------------------------------------
__global__ __launch_bounds__(256) void attn_kernel(
    const ushort* __restrict__ Qp, const ushort* __restrict__ Kp,
    const ushort* __restrict__ Vt, float* __restrict__ Out) {
    // per-wave P buffer: two halves (kv 0-31, 32-63), 16 rows x 40-ushort
    // stride (80B -> 2-way bank aliasing = free; 16B-aligned rows)
    __shared__ __align__(16) ushort Pbuf[4][1280];

    const int t = threadIdx.x;
    const int wid = t >> 6, lane = t & 63;
    const int lr = lane & 15, lg = lane >> 4;
    const int b = blockIdx.y;
    const int q0 = (blockIdx.x * 4 + wid) * 16;

    const ushort* Qb = Qp + (size_t)b * S_ * DH;
    const ushort* Kb = Kp + (size_t)b * S_ * DH;
    const ushort* Vb = Vt + (size_t)b * DH * S_;
    ushort* pb = &Pbuf[wid][0];

    // Q A-frags (16x32 each): lane holds row lr, k = lg*8..+8 (+32 for qf1)
    bf16x8 qf0 = *(const bf16x8*)&Qb[(size_t)(q0 + lr) * DH + lg * 8];
    bf16x8 qf1 = *(const bf16x8*)&Qb[(size_t)(q0 + lr) * DH + 32 + lg * 8];

    f32x4 o[4] = {};
    float m[4], lsum[4];
#pragma unroll
    for (int r = 0; r < 4; ++r) { m[r] = -1e30f; lsum[r] = 0.f; }

    const float scale = 0.125f;  // 1/sqrt(64)
    const int ktmax = q0 >> 6;   // last (partially masked) kv tile

    for (int kt = 0; kt <= ktmax; ++kt) {
        const int kv0 = kt * 64;

        // S = Q @ K^T : B-frag lane holds kv-col lr, d contiguous -> K rows
        f32x4 s[4];
#pragma unroll
        for (int cg = 0; cg < 4; ++cg) {
            const ushort* kr = &Kb[(size_t)(kv0 + cg * 16 + lr) * DH + lg * 8];
            bf16x8 k0 = *(const bf16x8*)kr;
            bf16x8 k1 = *(const bf16x8*)(kr + 32);
            f32x4 z = {};
            s[cg] = __builtin_amdgcn_mfma_f32_16x16x32_bf16(qf0, k0, z, 0, 0, 0);
            s[cg] = __builtin_amdgcn_mfma_f32_16x16x32_bf16(qf1, k1, s[cg], 0, 0, 0);
        }

        if (kt == ktmax) {
#pragma unroll
            for (int cg = 0; cg < 4; ++cg)
#pragma unroll
                for (int r = 0; r < 4; ++r) {
                    int kv = kv0 + cg * 16 + lr;
                    int q = q0 + lg * 4 + r;
                    s[cg][r] = (kv <= q) ? s[cg][r] * scale : -1e30f;
                }
        } else {
#pragma unroll
            for (int cg = 0; cg < 4; ++cg) s[cg] = s[cg] * scale;
        }

        // online softmax; row = lg*4+r lives in the 16 lanes sharing lg
        float mt[4], mn[4], corr[4], rs[4];
#pragma unroll
        for (int r = 0; r < 4; ++r)
            mt[r] = fmaxf(fmaxf(s[0][r], s[1][r]), fmaxf(s[2][r], s[3][r]));
#pragma unroll
        for (int r = 0; r < 4; ++r) {
#pragma unroll
            for (int msk = 1; msk < 16; msk <<= 1)
                mt[r] = fmaxf(mt[r], __shfl_xor(mt[r], msk));
            mn[r] = fmaxf(m[r], mt[r]);
            corr[r] = __expf(m[r] - mn[r]);
            m[r] = mn[r];
            rs[r] = 0.f;
        }
#pragma unroll
        for (int cg = 0; cg < 4; ++cg)
#pragma unroll
            for (int r = 0; r < 4; ++r) {
                float e = __expf(s[cg][r] - mn[r]);
                s[cg][r] = e;
                rs[r] += e;
            }
#pragma unroll
        for (int r = 0; r < 4; ++r) {
#pragma unroll
            for (int msk = 1; msk < 16; msk <<= 1) rs[r] += __shfl_xor(rs[r], msk);
            lsum[r] = lsum[r] * corr[r] + rs[r];
        }
#pragma unroll
        for (int fj = 0; fj < 4; ++fj)
#pragma unroll
            for (int r = 0; r < 4; ++r) o[fj][r] *= corr[r];

        // P (D-layout) -> LDS -> P (A-layout), bf16
#pragma unroll
        for (int cg = 0; cg < 4; ++cg) {
            int h = cg >> 1;
            int c = (cg & 1) * 16 + lr;
#pragma unroll
            for (int r = 0; r < 4; ++r)
                pb[h * 640 + (lg * 4 + r) * 40 + c] = f2bf(s[cg][r]);
        }
        asm volatile("s_waitcnt lgkmcnt(0)" ::: "memory");
        __builtin_amdgcn_sched_barrier(0);
        bf16x8 pa0 = *(bf16x8*)&pb[lr * 40 + lg * 8];
        bf16x8 pa1 = *(bf16x8*)&pb[640 + lr * 40 + lg * 8];
        asm volatile("" ::: "memory");  // keep these reads before next-iter writes

        // O += P @ V : V B-frag lane holds dh-col lr, kv contiguous -> Vt rows
#pragma unroll
        for (int fj = 0; fj < 4; ++fj) {
            const ushort* vr = &Vb[(size_t)(fj * 16 + lr) * S_ + kv0 + lg * 8];
            bf16x8 v0 = *(const bf16x8*)vr;
            bf16x8 v1 = *(const bf16x8*)(vr + 32);
            o[fj] = __builtin_amdgcn_mfma_f32_16x16x32_bf16(pa0, v0, o[fj], 0, 0, 0);
            o[fj] = __builtin_amdgcn_mfma_f32_16x16x32_bf16(pa1, v1, o[fj], 0, 0, 0);
        }
    }

#pragma unroll
    for (int fj = 0; fj < 4; ++fj)
#pragma unroll
        for (int r = 0; r < 4; ++r) {
            size_t row = (size_t)b * S_ + q0 + lg * 4 + r;
            Out[row * DH + fj * 16 + lr] = o[fj][r] / lsum[r];
        }
}

extern "C" void kernel_launch(void* const* d_in, const int* in_sizes, int n_in,
                              void* d_out, int out_size, void* d_ws,
                              size_t ws_size, hipStream_t stream) {
    const float* q_in = (const float*)d_in[0];
    const float* k_in = (const float*)d_in[1];
    const float* v_in = (const float*)d_in[2];
    const float* wq = (const float*)d_in[3];
    const float* wk = (const float*)d_in[4];
    const float* wv = (const float*)d_in[5];
    float* out = (float*)d_out;

    ushort* w = (ushort*)d_ws;
    const size_t MD = (size_t)M_ * DH;  // 1048576
    ushort* Qp = w;
    ushort* Kp = w + MD;
    ushort* Vt = w + 2 * MD;

    proj_kernel<<<dim3(M_ / 64, 3), 256, 0, stream>>>(q_in, k_in, v_in, wq, wk,
                                                      wv, Qp, Kp, Vt);
    attn_kernel<<<dim3(32, B_), 256, 0, stream>>>(Qp, Kp, Vt, out);
}

// Round 4
// 253.053 us; speedup vs baseline: 1.7223x; 1.2560x over previous
//
#include <hip/hip_runtime.h>
#include <hip/hip_bf16.h>
#include <stdint.h>

#define B_ 8
#define S_ 2048
#define DM 1024
#define DH 64
#define M_ (B_ * S_)  // 16384

typedef __attribute__((ext_vector_type(8))) short bf16x8;  // 8 bf16 = 4 VGPR
typedef __attribute__((ext_vector_type(4))) float f32x4;   // MFMA C/D frag

// fp32 -> bf16 round-to-nearest-even
__device__ __forceinline__ ushort f2bf(float x) {
    union { float f; uint32_t u; } v;
    v.f = x;
    uint32_t r = v.u + 0x7FFFu + ((v.u >> 16) & 1u);
    return (ushort)(r >> 16);
}

// ---------------------------------------------------------------------------
// W convert: 3 x [64][1024] fp32 -> bf16. 192 blocks x 256 thr x float4.
// ---------------------------------------------------------------------------
__global__ __launch_bounds__(256) void wconv_kernel(
    const float* __restrict__ W0, const float* __restrict__ W1,
    const float* __restrict__ W2, ushort* __restrict__ Wb) {
    int id = blockIdx.x * 256 + threadIdx.x;  // 0..49151
    int g = id >> 14;                         // 16384 float4 per W
    int off = (id & 16383) * 4;
    const float* W = (g == 0) ? W0 : (g == 1) ? W1 : W2;
    float4 w = *(const float4*)&W[off];
    ushort4 o;
    o.x = f2bf(w.x); o.y = f2bf(w.y); o.z = f2bf(w.z); o.w = f2bf(w.w);
    *(ushort4*)&Wb[g * 65536 + off] = o;
}

// ---------------------------------------------------------------------------
// Projection, LDS-free: each wave owns 16 rows x 64 heads.
// A-frag: lane reads X[(r0+lr)][kt + lg*8 .. +8] fp32 (32B) -> bf16 in reg.
// B-frag: lane reads Wb[head=fj*16+lr][kt + lg*8 .. +8] bf16 (16B, L2-hot).
// grid=(256,3) block=256 (4 waves = 64 rows/block), 12 waves/CU.
// D-layout (HW-verified): col = lane&15, row = (lane>>4)*4 + reg.
// ---------------------------------------------------------------------------
__global__ __launch_bounds__(256) void proj_kernel(
    const float* __restrict__ X0, const float* __restrict__ X1,
    const float* __restrict__ X2, const ushort* __restrict__ Wb,
    ushort* __restrict__ Qp, ushort* __restrict__ Kp,
    ushort* __restrict__ Vt) {
    const int g = blockIdx.y;
    const float* X = (g == 0) ? X0 : (g == 1) ? X1 : X2;
    const ushort* W = Wb + g * (DH * DM);

    const int t = threadIdx.x;
    const int wid = t >> 6, lane = t & 63;
    const int lr = lane & 15, lg = lane >> 4;
    const int r0 = blockIdx.x * 64 + wid * 16;

    const float* xp = X + (size_t)(r0 + lr) * DM + lg * 8;
    const ushort* wp = W + (size_t)lr * DM + lg * 8;

    f32x4 acc[4] = {};
#pragma unroll 2
    for (int kt = 0; kt < DM; kt += 32) {
        float4 x0 = *(const float4*)(xp + kt);
        float4 x1 = *(const float4*)(xp + kt + 4);
        bf16x8 a;
        a[0] = (short)f2bf(x0.x); a[1] = (short)f2bf(x0.y);
        a[2] = (short)f2bf(x0.z); a[3] = (short)f2bf(x0.w);
        a[4] = (short)f2bf(x1.x); a[5] = (short)f2bf(x1.y);
        a[6] = (short)f2bf(x1.z); a[7] = (short)f2bf(x1.w);
#pragma unroll
        for (int fj = 0; fj < 4; ++fj) {
            bf16x8 w = *(const bf16x8*)(wp + (size_t)fj * 16 * DM + kt);
            acc[fj] = __builtin_amdgcn_mfma_f32_16x16x32_bf16(a, w, acc[fj], 0, 0, 0);
        }
    }

    if (g < 2) {
        ushort* Y = (g == 0) ? Qp : Kp;
#pragma unroll
        for (int fj = 0; fj < 4; ++fj)
#pragma unroll
            for (int r = 0; r < 4; ++r)
                Y[(size_t)(r0 + lg * 4 + r) * DH + fj * 16 + lr] = f2bf(acc[fj][r]);
    } else {
        // V transposed: Vt[b][dh][s]; 4 consecutive s per lane -> ushort4.
        const int bb = r0 >> 11;
        const int s0 = (r0 & 2047) + lg * 4;
#pragma unroll
        for (int fj = 0; fj < 4; ++fj) {
            ushort4 pk;
            pk.x = f2bf(acc[fj][0]); pk.y = f2bf(acc[fj][1]);
            pk.z = f2bf(acc[fj][2]); pk.w = f2bf(acc[fj][3]);
            *(ushort4*)&Vt[((size_t)bb * DH + fj * 16 + lr) * S_ + s0] = pk;
        }
    }
}

// ---------------------------------------------------------------------------
// Causal flash attention: 16-row q-tile per block, 4-way KV-split (1 wave per
// kv stripe, kt = wid, wid+4, ...), partial (m,l,O) merged through LDS.
// Swapped QK^T: s[cg] = mfma(K,Q) so lane (lr,lg) holds P[q=lr][kv=cg*16+lg*4+r]
// -> row softmax = in-lane reduce over 16 + shfl_xor(16,32).
// Block jt mapping pairs complements so each CU's resident blocks have equal
// total work. grid=(1024) block=256; all blocks co-resident (27KB LDS).
// ---------------------------------------------------------------------------
__global__ __launch_bounds__(256) void attn_kernel(
    const ushort* __restrict__ Qp, const ushort* __restrict__ Kp,
    const ushort* __restrict__ Vt, float* __restrict__ Out) {
    __shared__ ushort Pb[4][16][72];  // per-wave P (144B rows: 16B-aligned, bank-spread)
    __shared__ float Ol[4][16][68];   // per-wave partial O (272B rows)
    __shared__ float Ml[4][16], Ll[4][16];

    const int t = threadIdx.x;
    const int wid = t >> 6, lane = t & 63;
    const int lr = lane & 15, lg = lane >> 4;

    const int id = blockIdx.x;
    const int b = id & 7, jx = id >> 3;
    const int u = jx & 31, v = jx >> 5;
    const int jt = (v & 1) ? (127 - (2 * u + (v >> 1))) : (2 * u + (v >> 1));
    const int q0 = jt * 16;
    const int ktmax = q0 >> 6;
    const int nt = ktmax + 1;

    const ushort* Qb = Qp + (size_t)b * S_ * DH;
    const ushort* Kb = Kp + (size_t)b * S_ * DH;
    const ushort* Vb = Vt + (size_t)b * DH * S_;

    bf16x8 qf0 = *(const bf16x8*)&Qb[(size_t)(q0 + lr) * DH + lg * 8];
    bf16x8 qf1 = *(const bf16x8*)&Qb[(size_t)(q0 + lr) * DH + 32 + lg * 8];

    f32x4 o[4] = {};
    float m = -1e30f, l = 0.f;  // state for q-row lr
    const float scale = 0.125f;

    for (int kt = wid; kt < nt; kt += 4) {
        const int kv0 = kt * 64;

        // S^T = K @ Q^T
        f32x4 s[4];
#pragma unroll
        for (int cg = 0; cg < 4; ++cg) {
            const ushort* kr = &Kb[(size_t)(kv0 + cg * 16 + lr) * DH + lg * 8];
            bf16x8 k0 = *(const bf16x8*)kr;
            bf16x8 k1 = *(const bf16x8*)(kr + 32);
            f32x4 z = {};
            s[cg] = __builtin_amdgcn_mfma_f32_16x16x32_bf16(k0, qf0, z, 0, 0, 0);
            s[cg] = __builtin_amdgcn_mfma_f32_16x16x32_bf16(k1, qf1, s[cg], 0, 0, 0);
        }

        // scale + causal mask (kv = kv0 + cg*16 + lg*4 + r, q = q0 + lr)
        if (kt == ktmax) {
#pragma unroll
            for (int cg = 0; cg < 4; ++cg)
#pragma unroll
                for (int r = 0; r < 4; ++r) {
                    int kv = kv0 + cg * 16 + lg * 4 + r;
                    s[cg][r] = (kv <= q0 + lr) ? s[cg][r] * scale : -1e30f;
                }
        } else {
#pragma unroll
            for (int cg = 0; cg < 4; ++cg) s[cg] = s[cg] * scale;
        }

        // online softmax for q-row lr (16 vals in-lane + 4 lanes via xor 16/32)
        float mx = -1e30f;
#pragma unroll
        for (int cg = 0; cg < 4; ++cg)
            mx = fmaxf(mx, fmaxf(fmaxf(s[cg][0], s[cg][1]),
                                 fmaxf(s[cg][2], s[cg][3])));
        mx = fmaxf(mx, __shfl_xor(mx, 16));
        mx = fmaxf(mx, __shfl_xor(mx, 32));
        float mn = fmaxf(m, mx);
        float corr = __expf(m - mn);
        m = mn;
        float rs = 0.f;
#pragma unroll
        for (int cg = 0; cg < 4; ++cg)
#pragma unroll
            for (int r = 0; r < 4; ++r) {
                float e = __expf(s[cg][r] - mn);
                s[cg][r] = e;
                rs += e;
            }
        rs += __shfl_xor(rs, 16);
        rs += __shfl_xor(rs, 32);
        l = l * corr + rs;

        // rescale O: its row is lg*4+r; fetch that row's corr from lane lg*4+r
        float co[4];
#pragma unroll
        for (int r = 0; r < 4; ++r) co[r] = __shfl(corr, lg * 4 + r);
#pragma unroll
        for (int fj = 0; fj < 4; ++fj)
#pragma unroll
            for (int r = 0; r < 4; ++r) o[fj][r] *= co[r];

        // P -> LDS (4 x b64) -> A-frags
#pragma unroll
        for (int cg = 0; cg < 4; ++cg) {
            ushort4 pk;
            pk.x = f2bf(s[cg][0]); pk.y = f2bf(s[cg][1]);
            pk.z = f2bf(s[cg][2]); pk.w = f2bf(s[cg][3]);
            *(ushort4*)&Pb[wid][lr][cg * 16 + lg * 4] = pk;
        }
        asm volatile("s_waitcnt lgkmcnt(0)" ::: "memory");
        __builtin_amdgcn_sched_barrier(0);
        bf16x8 pa0 = *(bf16x8*)&Pb[wid][lr][lg * 8];
        bf16x8 pa1 = *(bf16x8*)&Pb[wid][lr][32 + lg * 8];
        asm volatile("" ::: "memory");

        // O += P @ V
#pragma unroll
        for (int fj = 0; fj < 4; ++fj) {
            const ushort* vr = &Vb[(size_t)(fj * 16 + lr) * S_ + kv0 + lg * 8];
            bf16x8 v0 = *(const bf16x8*)vr;
            bf16x8 v1 = *(const bf16x8*)(vr + 32);
            o[fj] = __builtin_amdgcn_mfma_f32_16x16x32_bf16(pa0, v0, o[fj], 0, 0, 0);
            o[fj] = __builtin_amdgcn_mfma_f32_16x16x32_bf16(pa1, v1, o[fj], 0, 0, 0);
        }
    }

    // write unnormalized partials
#pragma unroll
    for (int fj = 0; fj < 4; ++fj)
#pragma unroll
        for (int r = 0; r < 4; ++r)
            Ol[wid][lg * 4 + r][fj * 16 + lr] = o[fj][r];
    if (lg == 0) {
        Ml[wid][lr] = m;
        Ll[wid][lr] = l;
    }
    __syncthreads();

    // merge 4 partials; thread t handles row t>>4, cols (t&15)*4..+4
    {
        const int row = t >> 4, c0 = (t & 15) * 4;
        float M = fmaxf(fmaxf(Ml[0][row], Ml[1][row]),
                        fmaxf(Ml[2][row], Ml[3][row]));
        float denom = 0.f;
        float a0 = 0.f, a1 = 0.f, a2 = 0.f, a3 = 0.f;
#pragma unroll
        for (int w = 0; w < 4; ++w) {
            float sc = __expf(Ml[w][row] - M);
            denom += Ll[w][row] * sc;
            float4 ov = *(const float4*)&Ol[w][row][c0];
            a0 += ov.x * sc; a1 += ov.y * sc; a2 += ov.z * sc; a3 += ov.w * sc;
        }
        float inv = 1.f / denom;
        float4 res = make_float4(a0 * inv, a1 * inv, a2 * inv, a3 * inv);
        *(float4*)&Out[((size_t)b * S_ + q0 + row) * DH + c0] = res;
    }
}

extern "C" void kernel_launch(void* const* d_in, const int* in_sizes, int n_in,
                              void* d_out, int out_size, void* d_ws,
                              size_t ws_size, hipStream_t stream) {
    const float* q_in = (const float*)d_in[0];
    const float* k_in = (const float*)d_in[1];
    const float* v_in = (const float*)d_in[2];
    const float* wq = (const float*)d_in[3];
    const float* wk = (const float*)d_in[4];
    const float* wv = (const float*)d_in[5];
    float* out = (float*)d_out;

    ushort* w = (ushort*)d_ws;
    const size_t MD = (size_t)M_ * DH;  // 1048576
    ushort* Qp = w;
    ushort* Kp = w + MD;
    ushort* Vt = w + 2 * MD;
    ushort* Wb = w + 3 * MD;  // 3*64*1024 bf16

    wconv_kernel<<<192, 256, 0, stream>>>(wq, wk, wv, Wb);
    proj_kernel<<<dim3(256, 3), 256, 0, stream>>>(q_in, k_in, v_in, Wb, Qp, Kp,
                                                  Vt);
    attn_kernel<<<1024, 256, 0, stream>>>(Qp, Kp, Vt, out);
}